// Round 14
// baseline (235.824 us; speedup 1.0000x reference)
//
#include <hip/hip_runtime.h>
#include <stdint.h>

#define T_STEPS 100
#define BB 4
#define NN 512
#define KK 10
#define LOG2E 1.4426950408889634

typedef float f4 __attribute__((ext_vector_type(4)));

// ---------------- threefry2x32 (JAX-compatible, 20 rounds) ----------------
__device__ __forceinline__ uint32_t rotl32(uint32_t v, int d) {
  return (v << d) | (v >> (32 - d));
}

__device__ __forceinline__ void tf2x32(uint32_t k0, uint32_t k1,
                                       uint32_t& x0, uint32_t& x1) {
  uint32_t k2 = k0 ^ k1 ^ 0x1BD11BDAu;
  x0 += k0; x1 += k1;
#define TFR(r) { x0 += x1; x1 = rotl32(x1, r); x1 ^= x0; }
  TFR(13) TFR(15) TFR(26) TFR(6)   x0 += k1; x1 += k2 + 1u;
  TFR(17) TFR(29) TFR(16) TFR(24)  x0 += k2; x1 += k0 + 2u;
  TFR(13) TFR(15) TFR(26) TFR(6)   x0 += k0; x1 += k1 + 3u;
  TFR(17) TFR(29) TFR(16) TFR(24)  x0 += k1; x1 += k2 + 4u;
  TFR(13) TFR(15) TFR(26) TFR(6)   x0 += k2; x1 += k0 + 5u;
#undef TFR
}

__device__ __forceinline__ float bits_to_u01(uint32_t bits) {
  return __fsub_rn(__uint_as_float((bits >> 9) | 0x3f800000u), 1.0f);
}

// XLA ErfInv32 (Giles)
__device__ __forceinline__ float erfinv_f32(float x) {
  float w = -logf(__fmul_rn(__fsub_rn(1.0f, x), __fadd_rn(1.0f, x)));
  float p;
  if (w < 5.0f) {
    w = __fsub_rn(w, 2.5f);
    p = 2.81022636e-08f;
    p = __fadd_rn(__fmul_rn(p, w), 3.43273939e-07f);
    p = __fadd_rn(__fmul_rn(p, w), -3.5233877e-06f);
    p = __fadd_rn(__fmul_rn(p, w), -4.39150654e-06f);
    p = __fadd_rn(__fmul_rn(p, w), 0.00021858087f);
    p = __fadd_rn(__fmul_rn(p, w), -0.00125372503f);
    p = __fadd_rn(__fmul_rn(p, w), -0.00417768164f);
    p = __fadd_rn(__fmul_rn(p, w), 0.246640727f);
    p = __fadd_rn(__fmul_rn(p, w), 1.50140941f);
  } else {
    w = __fsub_rn(sqrtf(w), 3.0f);
    p = -0.000200214257f;
    p = __fadd_rn(__fmul_rn(p, w), 0.000100950558f);
    p = __fadd_rn(__fmul_rn(p, w), 0.00134934322f);
    p = __fadd_rn(__fmul_rn(p, w), -0.00367342844f);
    p = __fadd_rn(__fmul_rn(p, w), 0.00573950773f);
    p = __fadd_rn(__fmul_rn(p, w), -0.0076224613f);
    p = __fadd_rn(__fmul_rn(p, w), 0.00943887047f);
    p = __fadd_rn(__fmul_rn(p, w), 1.00167406f);
    p = __fadd_rn(__fmul_rn(p, w), 2.83297682f);
  }
  return __fmul_rn(p, x);
}

// fast sigmoid
__device__ __forceinline__ float fast_sigmoid(float x) {
  float e = __expf(-x);
  return __builtin_amdgcn_rcpf(__fadd_rn(1.0f, e));
}

template <int CTRL>
__device__ __forceinline__ float dpp_add(float x) {
  int v = __builtin_amdgcn_update_dpp(0, __float_as_int(x), CTRL, 0xF, 0xF, true);
  return __fadd_rn(x, __int_as_float(v));
}
__device__ __forceinline__ float readlane_f(float x, int lane) {
  return __int_as_float(__builtin_amdgcn_readlane(__float_as_int(x), lane));
}
// full 64-lane sum -> uniform value (DPP tree + 4 readlanes; verified r7-r13)
__device__ __forceinline__ float wave_tot(float ps) {
  ps = dpp_add<0xB1>(ps);
  ps = dpp_add<0x4E>(ps);
  ps = dpp_add<0x141>(ps);
  ps = dpp_add<0x140>(ps);
  float s0 = readlane_f(ps, 0), s1 = readlane_f(ps, 16);
  float s2 = readlane_f(ps, 32), s3 = readlane_f(ps, 48);
  return __fadd_rn(__fadd_rn(s0, s1), __fadd_rn(s2, s3));
}
// per-lane partial: sum of min(exp2(arg),1) over the lane's 8 j's
__device__ __forceinline__ float eval8(f4 a0, f4 a1) {
  f4 E0, E1;
  #pragma unroll
  for (int c = 0; c < 4; c++) {
    E0[c] = fminf(exp2f(a0[c]), 1.0f);
    E1[c] = fminf(exp2f(a1[c]), 1.0f);
  }
  f4 Es = E0 + E1;
  return __fadd_rn(__fadd_rn(Es[0], Es[1]), __fadd_rn(Es[2], Es[3]));
}

// ------ Kernel C: fused rng+prep+ll (+Tsum); blocks [0,400) llt, [400,416) ll0
__global__ __launch_bounds__(512) void ll_kernel(const float* __restrict__ mu,
                                                 const float* __restrict__ sig,
                                                 const float* __restrict__ pi,
                                                 const float* __restrict__ A0,
                                                 float* __restrict__ pm,
                                                 float* __restrict__ uacc,
                                                 float* __restrict__ llt,
                                                 float* __restrict__ ll0,
                                                 float* __restrict__ tsum) {
  __shared__ float spm[BB][NN];
  __shared__ float sL[BB][NN];
  __shared__ double pt[4][128];
  int tid = threadIdx.x;
  int q = tid >> 7, jj = tid & 127;
  int bi = blockIdx.x;
  if (bi < 400) {
    int t = bi >> 2, jc = bi & 3;
    uint32_t kk0 = 0u, kk1 = (uint32_t)t;
    tf2x32(0u, 42u, kk0, kk1);
    uint32_t n0 = 0u, n1 = 0u; tf2x32(kk0, kk1, n0, n1);   // k_noise
    #pragma unroll
    for (int b = 0; b < BB; b++) {
      int m = b * NN + tid;
      const float* pp = pi + m * KK;
      float mx = pp[0];
      for (int k = 1; k < KK; k++) mx = fmaxf(mx, pp[k]);
      float e[KK]; float s = 0.0f;
      for (int k = 0; k < KK; k++) { e[k] = expf(__fsub_rn(pp[k], mx)); s = __fadd_rn(s, e[k]); }
      float smv = 0.0f, ssv = 0.0f, eps = 0.0f;
      for (int k = 0; k < KK; k++) {
        float p = e[k] / s;
        smv = __fadd_rn(smv, __fmul_rn(p, mu[m * KK + k]));
        ssv = __fadd_rn(ssv, __fmul_rn(p, sig[m * KK + k]));
        eps = __fadd_rn(eps, pp[k]);
      }
      float ep = fminf(fmaxf(eps, 1e-8f), 1.0f);
      float lep = logf(ep);
      float l1 = logf(__fsub_rn(1.0f, ep));
      sL[b][tid] = (float)((double)lep - (double)l1);

      uint32_t y0 = 0u, y1 = (uint32_t)m;
      tf2x32(n0, n1, y0, y1);
      uint32_t bits = y0 ^ y1;
      float u01 = bits_to_u01(bits);
      const float lo = -0.99999994f;
      float u = fmaxf(lo, __fadd_rn(__fmul_rn(u01, 2.0f), lo));
      float z = __fmul_rn(1.41421356237309515f, erfinv_f32(u));
      float pmv = __fadd_rn(smv, __fmul_rn(z, ssv));
      spm[b][tid] = pmv;
      if (jc == 0) pm[(t * 4 + b) * NN + tid] = pmv;
    }
    if (jc == 0 && tid < 4) {
      uint32_t u0 = 0u, u1 = 1u; tf2x32(kk0, kk1, u0, u1); // k_unif
      uint32_t c0 = 0u, c1 = (uint32_t)tid;
      tf2x32(u0, u1, c0, c1);
      uacc[t * 4 + tid] = __fmul_rn(bits_to_u01(c0 ^ c1), 512.0f);
    }
    __syncthreads();
    int i0 = q * 128;
    double tsd = 0.0;
    for (int b = 0; b < BB; b++) {
      float pmj = spm[b][jc * 128 + jj];
      double acc = 0.0;
      #pragma unroll 8
      for (int i = 0; i < 128; i += 2) {
        float x0 = __fmul_rn(spm[b][i0 + i], pmj);
        float x1 = __fmul_rn(spm[b][i0 + i + 1], pmj);
        float t0 = __fmul_rn(fast_sigmoid(x0), sL[b][i0 + i]);
        float t1 = __fmul_rn(fast_sigmoid(x1), sL[b][i0 + i + 1]);
        acc += (double)__fadd_rn(t0, t1);
      }
      pt[q][jj] = acc;
      __syncthreads();
      if (tid < 128) {
        double a = ((pt[0][jj] + pt[1][jj]) + pt[2][jj]) + pt[3][jj];
        llt[(t * 4 + b) * NN + jc * 128 + jj] = (float)(a * LOG2E);
        tsd += a;
      }
      __syncthreads();
    }
    if (tid < 128) tsum[t * NN + jc * 128 + jj] = (float)(tsd * LOG2E);
  } else {
    int idx = bi - 400;
    int b = idx >> 2, jc = idx & 3;
    {
      int m = b * NN + tid;
      const float* pp = pi + m * KK;
      float eps = 0.0f;
      for (int k = 0; k < KK; k++) eps = __fadd_rn(eps, pp[k]);
      float ep = fminf(fmaxf(eps, 1e-8f), 1.0f);
      float lep = logf(ep);
      float l1 = logf(__fsub_rn(1.0f, ep));
      sL[0][tid] = (float)((double)lep - (double)l1);
    }
    __syncthreads();
    int j = jc * 128 + jj;
    int i0 = q * 128;
    double acc = 0.0;
    #pragma unroll 4
    for (int i = 0; i < 128; i++) {
      acc += (double)A0[(size_t)(i0 + i) * NN + j] * (double)sL[0][i0 + i];
    }
    pt[q][jj] = acc;
    __syncthreads();
    if (tid < 128) {
      double a = ((pt[0][jj] + pt[1][jj]) + pt[2][jj]) + pt[3][jj];
      ll0[b * NN + jc * 128 + jj] = (float)(a * LOG2E);
    }
  }
}

// ------- Kernel D: 8-wave speculative-pair chain (50 barrier rounds) --------
// Chain state (cur/C/st) REPLICATED per wave; decisions are uniform (computed
// from shared LDS red values) so replicas stay identical.  Per pair: wave 0
// evals step-t0's ratio; waves 1-5 eval the 5 nested candidates for t1; one
// raw (lgkmcnt-only) barrier; all waves resolve both steps identically.
#define CH_RAW_BARRIER() asm volatile("s_waitcnt lgkmcnt(0)\n\ts_barrier" ::: "memory")

#define PAIR_LOAD(BUF, P)                                                    \
  {                                                                          \
    int t0_ = 2 * (P), t1_ = t0_ + 1;                                        \
    BUF##Te0 = tsv[(size_t)t0_ * 128 + g];                                   \
    BUF##Te1 = tsv[(size_t)t0_ * 128 + 64 + g];                              \
    BUF##To0 = tsv[(size_t)t1_ * 128 + g];                                   \
    BUF##To1 = tsv[(size_t)t1_ * 128 + 64 + g];                              \
    _Pragma("unroll")                                                        \
    for (int b = 0; b < 4; b++) {                                            \
      _Pragma("unroll")                                                      \
      for (int k = 0; k < 2; k++) {                                          \
        BUF##Re[b * 2 + k] = lltv[((size_t)t0_ * 4 + b) * 128 + k * 64 + g]; \
        BUF##Ro[b * 2 + k] = lltv[((size_t)t1_ * 4 + b) * 128 + k * 64 + g]; \
      }                                                                      \
    }                                                                        \
  }

#define PAIR_STEP(BUF, P)                                                    \
  {                                                                          \
    int t0_ = 2 * (P), t1_ = t0_ + 1;                                        \
    float4 ue = sua[t0_], uo = sua[t1_];                                     \
    int re0 = (ue.y < ue.x) + (ue.z < ue.x) + (ue.w < ue.x);                 \
    int re1 = (ue.x <= ue.y) + (ue.z < ue.y) + (ue.w < ue.y);                 \
    int re2 = (ue.x <= ue.z) + (ue.y <= ue.z) + (ue.w < ue.z);               \
    int re3 = (ue.x <= ue.w) + (ue.y <= ue.w) + (ue.z <= ue.w);              \
    float myps;                                                              \
    if (wid == 0) {                                                          \
      myps = eval8(BUF##Te0 - C0, BUF##Te1 - C1);                            \
    } else {                                                                 \
      int kk = wid - 1;                                                      \
      f4 pk0 = {}, pk1 = {};                                                 \
      if (re0 < kk) { pk0 += BUF##Re[0] - cur[0]; pk1 += BUF##Re[1] - cur[1]; } \
      if (re1 < kk) { pk0 += BUF##Re[2] - cur[2]; pk1 += BUF##Re[3] - cur[3]; } \
      if (re2 < kk) { pk0 += BUF##Re[4] - cur[4]; pk1 += BUF##Re[5] - cur[5]; } \
      if (re3 < kk) { pk0 += BUF##Re[6] - cur[6]; pk1 += BUF##Re[7] - cur[7]; } \
      myps = eval8((BUF##To0 - C0) - pk0, (BUF##To1 - C1) - pk1);            \
    }                                                                        \
    float tot = wave_tot(myps);                                              \
    if (g == 0 && wid < 6) red[(P) & 1][wid] = tot;                          \
    CH_RAW_BARRIER();                                                        \
    float t0v = red[(P) & 1][0];                                             \
    int kt = (ue.x < t0v) + (ue.y < t0v) + (ue.z < t0v) + (ue.w < t0v);      \
    kt = __builtin_amdgcn_readfirstlane(kt);                                 \
    float r1v = red[(P) & 1][1 + kt];                                        \
    int ko = (uo.x < r1v) + (uo.y < r1v) + (uo.z < r1v) + (uo.w < r1v);      \
    ko = __builtin_amdgcn_readfirstlane(ko);                                 \
    int ro0 = (uo.y < uo.x) + (uo.z < uo.x) + (uo.w < uo.x);                 \
    int ro1 = (uo.x <= uo.y) + (uo.z < uo.y) + (uo.w < uo.y);                \
    int ro2 = (uo.x <= uo.z) + (uo.y <= uo.z) + (uo.w < uo.z);               \
    int ro3 = (uo.x <= uo.w) + (uo.y <= uo.w) + (uo.z <= uo.w);              \
    int sp0 = (re0 < kt) ? t0_ : st0, sp1 = (re1 < kt) ? t0_ : st1;          \
    int sp2 = (re2 < kt) ? t0_ : st2, sp3 = (re3 < kt) ? t0_ : st3;          \
    if (kt | ko) {                                                           \
      if (ro0 < ko)      { st0 = t1_; cur[0] = BUF##Ro[0]; cur[1] = BUF##Ro[1]; } \
      else if (re0 < kt) { st0 = t0_; cur[0] = BUF##Re[0]; cur[1] = BUF##Re[1]; } \
      if (ro1 < ko)      { st1 = t1_; cur[2] = BUF##Ro[2]; cur[3] = BUF##Ro[3]; } \
      else if (re1 < kt) { st1 = t0_; cur[2] = BUF##Re[2]; cur[3] = BUF##Re[3]; } \
      if (ro2 < ko)      { st2 = t1_; cur[4] = BUF##Ro[4]; cur[5] = BUF##Ro[5]; } \
      else if (re2 < kt) { st2 = t0_; cur[4] = BUF##Re[4]; cur[5] = BUF##Re[5]; } \
      if (ro3 < ko)      { st3 = t1_; cur[6] = BUF##Ro[6]; cur[7] = BUF##Ro[7]; } \
      else if (re3 < kt) { st3 = t0_; cur[6] = BUF##Re[6]; cur[7] = BUF##Re[7]; } \
      C0 = (cur[0] + cur[2]) + (cur[4] + cur[6]);                            \
      C1 = (cur[1] + cur[3]) + (cur[5] + cur[7]);                            \
    }                                                                        \
    if (tid == 0) {                                                          \
      spk[t0_] = (uint32_t)(sp0 + 1) | ((uint32_t)(sp1 + 1) << 8) |          \
                 ((uint32_t)(sp2 + 1) << 16) | ((uint32_t)(sp3 + 1) << 24);  \
      spk[t1_] = (uint32_t)(st0 + 1) | ((uint32_t)(st1 + 1) << 8) |          \
                 ((uint32_t)(st2 + 1) << 16) | ((uint32_t)(st3 + 1) << 24);  \
    }                                                                        \
  }

__global__ __launch_bounds__(512, 1) void chain_kernel(const float* __restrict__ llt,
                                                       const float* __restrict__ tsum,
                                                       const float* __restrict__ ll0,
                                                       const float* __restrict__ uacc,
                                                       int* __restrict__ slist,
                                                       float* __restrict__ wlist,
                                                       int* __restrict__ Mv) {
  __shared__ float4 sua[T_STEPS];
  __shared__ uint32_t spk[T_STEPS];
  __shared__ float red[2][8];
  __shared__ int scnt[BB][101];
  int tid = threadIdx.x;
  int g = tid & 63;
  int wid = tid >> 6;

  if (tid < T_STEPS) sua[tid] = ((const float4*)uacc)[tid];

  const f4* lltv = (const f4*)llt;
  const f4* tsv  = (const f4*)tsum;
  const f4* ll0v = (const f4*)ll0;

  // replicated per-wave chain state
  f4 cur[8];
  #pragma unroll
  for (int b = 0; b < 4; b++)
    #pragma unroll
    for (int k = 0; k < 2; k++) cur[b * 2 + k] = ll0v[b * 128 + k * 64 + g];
  f4 C0 = (cur[0] + cur[2]) + (cur[4] + cur[6]);
  f4 C1 = (cur[1] + cur[3]) + (cur[5] + cur[7]);
  int st0 = -1, st1 = -1, st2 = -1, st3 = -1;

  f4 ATe0, ATe1, ATo0, ATo1, ARe[8], ARo[8];
  f4 BTe0, BTe1, BTo0, BTo1, BRe[8], BRo[8];
  PAIR_LOAD(A, 0)
  PAIR_LOAD(B, 1)
  __syncthreads();  // sua ready

  for (int p = 0; p < 50; p += 2) {
    PAIR_STEP(A, p)
    if (p + 2 < 50) PAIR_LOAD(A, p + 2)
    PAIR_STEP(B, p + 1)
    if (p + 3 < 50) PAIR_LOAD(B, p + 3)
  }

  // ---- epilogue: histogram + compacted (state, weight) list ----
  __syncthreads();
  for (int s = tid; s < BB * 101; s += 512) (&scnt[0][0])[s] = 0;
  __syncthreads();
  if (tid < T_STEPS) {
    uint32_t p0 = spk[tid];
    atomicAdd(&scnt[0][p0 & 255], 1);
    atomicAdd(&scnt[1][(p0 >> 8) & 255], 1);
    atomicAdd(&scnt[2][(p0 >> 16) & 255], 1);
    atomicAdd(&scnt[3][p0 >> 24], 1);
  }
  __syncthreads();
  if (tid < 4) {
    int m = 0;
    for (int s = 0; s <= 100; s++) {
      int c = scnt[tid][s];
      if (c) { slist[tid * 104 + m] = s; wlist[tid * 104 + m] = (float)c; m++; }
    }
    Mv[tid] = m;
  }
}

// ---------------- Kernel E: out via compacted state list --------------------
__global__ __launch_bounds__(512) void out_kernel(const float* __restrict__ pm,
                                                  const float* __restrict__ A0,
                                                  const int* __restrict__ slist,
                                                  const float* __restrict__ wlist,
                                                  const int* __restrict__ Mv,
                                                  float* __restrict__ out) {
  int b = blockIdx.x >> 9;
  int i = blockIdx.x & 511;
  int j = threadIdx.x;
  int M = Mv[b];
  float r = 0.0f;
  for (int e = 0; e < M; e++) {
    int s = slist[b * 104 + e];
    float w = wlist[b * 104 + e];
    if (s == 0) {
      r += w * A0[(size_t)i * NN + j];
    } else {
      int t = s - 1;
      float pmi = pm[(size_t)(t * BB + b) * NN + i];
      float pmj = pm[(size_t)(t * BB + b) * NN + j];
      r += w * fast_sigmoid(__fmul_rn(pmi, pmj));
    }
  }
  out[((size_t)b * NN + i) * NN + j] = r * 0.01f;
}

extern "C" void kernel_launch(void* const* d_in, const int* in_sizes, int n_in,
                              void* d_out, int out_size, void* d_ws, size_t ws_size,
                              hipStream_t stream) {
  const float* mu  = (const float*)d_in[0];
  const float* sig = (const float*)d_in[1];
  const float* pi  = (const float*)d_in[2];
  const float* A0  = (const float*)d_in[3];

  char* ws = (char*)d_ws;
  size_t off = 0;
  auto alloc = [&](size_t bytes) -> char* {
    char* p = ws + off;
    off += (bytes + 255) & ~(size_t)255;
    return p;
  };
  float* llt   = (float*)alloc((size_t)T_STEPS * BB * NN * 4); // 819,200
  float* tsum  = (float*)alloc((size_t)T_STEPS * NN * 4);      // 204,800
  float* ll0   = (float*)alloc(BB * NN * 4);                   // 8,192
  float* pm    = (float*)alloc((size_t)T_STEPS * BB * NN * 4); // 819,200
  float* uacc  = (float*)alloc(T_STEPS * 4 * 4);
  int*   slist = (int*)alloc(BB * 104 * 4);
  float* wlist = (float*)alloc(BB * 104 * 4);
  int*   Mv    = (int*)alloc(4 * 4);
  float* outp  = (float*)d_out;

  ll_kernel<<<416, 512, 0, stream>>>(mu, sig, pi, A0, pm, uacc, llt, ll0, tsum);
  chain_kernel<<<1, 512, 0, stream>>>(llt, tsum, ll0, uacc, slist, wlist, Mv);
  out_kernel<<<BB * NN, 512, 0, stream>>>(pm, A0, slist, wlist, Mv, outp);
}

// Round 15
// 150.648 us; speedup vs baseline: 1.5654x; 1.5654x over previous
//
#include <hip/hip_runtime.h>
#include <stdint.h>

#define T_STEPS 100
#define BB 4
#define NN 512
#define KK 10
#define LOG2E 1.4426950408889634

typedef float f4 __attribute__((ext_vector_type(4)));

// ---------------- threefry2x32 (JAX-compatible, 20 rounds) ----------------
__device__ __forceinline__ uint32_t rotl32(uint32_t v, int d) {
  return (v << d) | (v >> (32 - d));
}

__device__ __forceinline__ void tf2x32(uint32_t k0, uint32_t k1,
                                       uint32_t& x0, uint32_t& x1) {
  uint32_t k2 = k0 ^ k1 ^ 0x1BD11BDAu;
  x0 += k0; x1 += k1;
#define TFR(r) { x0 += x1; x1 = rotl32(x1, r); x1 ^= x0; }
  TFR(13) TFR(15) TFR(26) TFR(6)   x0 += k1; x1 += k2 + 1u;
  TFR(17) TFR(29) TFR(16) TFR(24)  x0 += k2; x1 += k0 + 2u;
  TFR(13) TFR(15) TFR(26) TFR(6)   x0 += k0; x1 += k1 + 3u;
  TFR(17) TFR(29) TFR(16) TFR(24)  x0 += k1; x1 += k2 + 4u;
  TFR(13) TFR(15) TFR(26) TFR(6)   x0 += k2; x1 += k0 + 5u;
#undef TFR
}

__device__ __forceinline__ float bits_to_u01(uint32_t bits) {
  return __fsub_rn(__uint_as_float((bits >> 9) | 0x3f800000u), 1.0f);
}

// XLA ErfInv32 (Giles)
__device__ __forceinline__ float erfinv_f32(float x) {
  float w = -logf(__fmul_rn(__fsub_rn(1.0f, x), __fadd_rn(1.0f, x)));
  float p;
  if (w < 5.0f) {
    w = __fsub_rn(w, 2.5f);
    p = 2.81022636e-08f;
    p = __fadd_rn(__fmul_rn(p, w), 3.43273939e-07f);
    p = __fadd_rn(__fmul_rn(p, w), -3.5233877e-06f);
    p = __fadd_rn(__fmul_rn(p, w), -4.39150654e-06f);
    p = __fadd_rn(__fmul_rn(p, w), 0.00021858087f);
    p = __fadd_rn(__fmul_rn(p, w), -0.00125372503f);
    p = __fadd_rn(__fmul_rn(p, w), -0.00417768164f);
    p = __fadd_rn(__fmul_rn(p, w), 0.246640727f);
    p = __fadd_rn(__fmul_rn(p, w), 1.50140941f);
  } else {
    w = __fsub_rn(sqrtf(w), 3.0f);
    p = -0.000200214257f;
    p = __fadd_rn(__fmul_rn(p, w), 0.000100950558f);
    p = __fadd_rn(__fmul_rn(p, w), 0.00134934322f);
    p = __fadd_rn(__fmul_rn(p, w), -0.00367342844f);
    p = __fadd_rn(__fmul_rn(p, w), 0.00573950773f);
    p = __fadd_rn(__fmul_rn(p, w), -0.0076224613f);
    p = __fadd_rn(__fmul_rn(p, w), 0.00943887047f);
    p = __fadd_rn(__fmul_rn(p, w), 1.00167406f);
    p = __fadd_rn(__fmul_rn(p, w), 2.83297682f);
  }
  return __fmul_rn(p, x);
}

// fast sigmoid: 1/(1+exp(-x)) via native exp + native rcp
__device__ __forceinline__ float fast_sigmoid(float x) {
  float e = __expf(-x);
  return __builtin_amdgcn_rcpf(__fadd_rn(1.0f, e));
}

template <int CTRL>
__device__ __forceinline__ float dpp_add(float x) {
  int v = __builtin_amdgcn_update_dpp(0, __float_as_int(x), CTRL, 0xF, 0xF, true);
  return __fadd_rn(x, __int_as_float(v));
}

// ------ Kernel C: fused prep+rng+ll.  Blocks [0,1600): (tb=t*4+b, jc);
// each thread recomputes prep+rng for its single m = b*512+tid with the
// EXACT float sequence of the verified rng_kernel (bit-identical pm/Lf/uacc).
// jc==0 blocks also publish pm (and tb%4==0 ones publish uacc).
// Blocks [1600,1616): ll0 (b, jc) with per-thread Lf recompute.
__global__ __launch_bounds__(512) void ll_kernel(const float* __restrict__ mu,
                                                 const float* __restrict__ sig,
                                                 const float* __restrict__ pi,
                                                 const float* __restrict__ A0,
                                                 float* __restrict__ pm,
                                                 float* __restrict__ uacc,
                                                 float* __restrict__ llt,
                                                 float* __restrict__ ll0) {
  __shared__ float spm[NN];
  __shared__ float sLc[NN];
  __shared__ double pt[4][128];
  int tid = threadIdx.x;
  int q = tid >> 7, jj = tid & 127;
  int bi = blockIdx.x;
  if (bi < 1600) {
    int tb = bi >> 2, jc = bi & 3;
    int t = tb >> 2, b = tb & 3;
    // --- prep (identical rounding to the verified prep/rng kernel) ---
    {
      int m = b * NN + tid;
      const float* pp = pi + m * KK;
      float mx = pp[0];
      for (int k = 1; k < KK; k++) mx = fmaxf(mx, pp[k]);
      float e[KK]; float s = 0.0f;
      for (int k = 0; k < KK; k++) { e[k] = expf(__fsub_rn(pp[k], mx)); s = __fadd_rn(s, e[k]); }
      float smv = 0.0f, ssv = 0.0f, eps = 0.0f;
      for (int k = 0; k < KK; k++) {
        float p = e[k] / s;
        smv = __fadd_rn(smv, __fmul_rn(p, mu[m * KK + k]));
        ssv = __fadd_rn(ssv, __fmul_rn(p, sig[m * KK + k]));
        eps = __fadd_rn(eps, pp[k]);
      }
      float ep = fminf(fmaxf(eps, 1e-8f), 1.0f);
      float lep = logf(ep);
      float l1 = logf(__fsub_rn(1.0f, ep));
      sLc[tid] = (float)((double)lep - (double)l1);

      // --- partitionable threefry (identical to verified rng_kernel) ---
      uint32_t kk0 = 0u, kk1 = (uint32_t)t;
      tf2x32(0u, 42u, kk0, kk1);
      uint32_t n0 = 0u, n1 = 0u; tf2x32(kk0, kk1, n0, n1);   // k_noise
      uint32_t y0 = 0u, y1 = (uint32_t)m;
      tf2x32(n0, n1, y0, y1);
      uint32_t bits = y0 ^ y1;
      float u01 = bits_to_u01(bits);
      const float lo = -0.99999994f;
      float u = fmaxf(lo, __fadd_rn(__fmul_rn(u01, 2.0f), lo));
      float z = __fmul_rn(1.41421356237309515f, erfinv_f32(u));
      float pmv = __fadd_rn(smv, __fmul_rn(z, ssv));
      spm[tid] = pmv;
      if (jc == 0) pm[tb * NN + tid] = pmv;
      if (jc == 0 && b == 0 && tid < 4) {
        uint32_t u0 = 0u, u1 = 1u; tf2x32(kk0, kk1, u0, u1); // k_unif
        uint32_t c0 = 0u, c1 = (uint32_t)tid;
        tf2x32(u0, u1, c0, c1);
        uacc[t * 4 + tid] = __fmul_rn(bits_to_u01(c0 ^ c1), 512.0f);
      }
    }
    __syncthreads();
    int j = jc * 128 + jj;
    float pmj = spm[j];
    int i0 = q * 128;
    double acc = 0.0;
    #pragma unroll 8
    for (int i = 0; i < 128; i += 2) {
      float x0 = __fmul_rn(spm[i0 + i], pmj);
      float x1 = __fmul_rn(spm[i0 + i + 1], pmj);
      float t0 = __fmul_rn(fast_sigmoid(x0), sLc[i0 + i]);
      float t1 = __fmul_rn(fast_sigmoid(x1), sLc[i0 + i + 1]);
      acc += (double)__fadd_rn(t0, t1);
    }
    pt[q][jj] = acc;
    __syncthreads();
    if (tid < 128) {
      double a = ((pt[0][jj] + pt[1][jj]) + pt[2][jj]) + pt[3][jj];
      llt[tb * NN + jc * 128 + jj] = (float)(a * LOG2E);
    }
  } else {
    int idx = bi - 1600;
    int b = idx >> 2, jc = idx & 3;
    {
      int m = b * NN + tid;
      const float* pp = pi + m * KK;
      float eps = 0.0f;
      for (int k = 0; k < KK; k++) eps = __fadd_rn(eps, pp[k]);
      float ep = fminf(fmaxf(eps, 1e-8f), 1.0f);
      float lep = logf(ep);
      float l1 = logf(__fsub_rn(1.0f, ep));
      sLc[tid] = (float)((double)lep - (double)l1);
    }
    __syncthreads();
    int j = jc * 128 + jj;
    int i0 = q * 128;
    double acc = 0.0;
    #pragma unroll 4
    for (int i = 0; i < 128; i++) {
      acc += (double)A0[(size_t)(i0 + i) * NN + j] * (double)sLc[i0 + i];
    }
    pt[q][jj] = acc;
    __syncthreads();
    if (tid < 128) {
      double a = ((pt[0][jj] + pt[1][jj]) + pt[2][jj]) + pt[3][jj];
      ll0[b * NN + jc * 128 + jj] = (float)(a * LOG2E);
    }
  }
}

// ------- Kernel D: lean f32 single-wave chain (round-11 verbatim) ----------
#define CH_LOAD(P, T)                                                        \
  {                                                                          \
    _Pragma("unroll")                                                        \
    for (int b = 0; b < 4; b++) {                                            \
      _Pragma("unroll")                                                      \
      for (int k = 0; k < 2; k++)                                            \
        P[b * 2 + k] = lltv[((size_t)(T) * 4 + b) * 128 + k * 64 + g];       \
    }                                                                        \
  }

#define CH_STEP(P, T)                                                        \
  {                                                                          \
    float4 ua = uaccv[T];                                                    \
    f4 tp0 = (P[0] + P[2]) + (P[4] + P[6]);                                  \
    f4 tp1 = (P[1] + P[3]) + (P[5] + P[7]);                                  \
    f4 d0 = tp0 - S0;                                                        \
    f4 d1 = tp1 - S1;                                                        \
    f4 E0, E1;                                                               \
    _Pragma("unroll")                                                        \
    for (int c = 0; c < 4; c++) {                                            \
      E0[c] = fminf(exp2f(d0[c]), 1.0f);                                     \
      E1[c] = fminf(exp2f(d1[c]), 1.0f);                                     \
    }                                                                        \
    f4 Es = E0 + E1;                                                         \
    float ps = __fadd_rn(__fadd_rn(Es[0], Es[1]), __fadd_rn(Es[2], Es[3]));  \
    ps = dpp_add<0xB1>(ps);   /* xor1 */                                     \
    ps = dpp_add<0x4E>(ps);   /* xor2 */                                     \
    ps = dpp_add<0x141>(ps);  /* xor4 (half-mirror) */                       \
    ps = dpp_add<0x140>(ps);  /* xor8 (mirror) */                            \
    ps = __fadd_rn(ps, __int_as_float(__builtin_amdgcn_ds_swizzle(           \
             __float_as_int(ps), 0x401F)));  /* xor16 */                     \
    ps = __fadd_rn(ps, __int_as_float(__builtin_amdgcn_ds_bpermute(          \
             lx32, __float_as_int(ps))));    /* xor32 */                     \
    if (ua.x < ps) { st0 = (T); cur[0] = P[0]; cur[1] = P[1]; }              \
    if (ua.y < ps) { st1 = (T); cur[2] = P[2]; cur[3] = P[3]; }              \
    if (ua.z < ps) { st2 = (T); cur[4] = P[4]; cur[5] = P[5]; }              \
    if (ua.w < ps) { st3 = (T); cur[6] = P[6]; cur[7] = P[7]; }              \
    S0 = (cur[0] + cur[2]) + (cur[4] + cur[6]);                              \
    S1 = (cur[1] + cur[3]) + (cur[5] + cur[7]);                              \
    if (g == 0) {                                                            \
      uint32_t pk = (uint32_t)(st0 + 1) | ((uint32_t)(st1 + 1) << 8) |       \
                    ((uint32_t)(st2 + 1) << 16) | ((uint32_t)(st3 + 1) << 24);\
      spk[T] = pk;                                                           \
    }                                                                        \
  }

__global__ __launch_bounds__(64, 1) void chain_kernel(const float* __restrict__ llt,
                                                      const float* __restrict__ ll0,
                                                      const float* __restrict__ uacc,
                                                      int* __restrict__ slist,
                                                      float* __restrict__ wlist,
                                                      int* __restrict__ Mv) {
  __shared__ uint32_t spk[T_STEPS];
  __shared__ int scnt[BB][101];
  int g = threadIdx.x;
  int lx32 = (g ^ 32) << 2;

  const f4* lltv = (const f4*)llt;
  const f4* ll0v = (const f4*)ll0;
  const float4* uaccv = (const float4*)uacc;

  f4 cur[8];
  #pragma unroll
  for (int b = 0; b < 4; b++)
    #pragma unroll
    for (int k = 0; k < 2; k++) cur[b * 2 + k] = ll0v[b * 128 + k * 64 + g];
  f4 S0 = (cur[0] + cur[2]) + (cur[4] + cur[6]);
  f4 S1 = (cur[1] + cur[3]) + (cur[5] + cur[7]);
  int st0 = -1, st1 = -1, st2 = -1, st3 = -1;

  f4 Pa[8], Pb[8], Pc[8];
  CH_LOAD(Pa, 0)
  CH_LOAD(Pb, 1)
  CH_LOAD(Pc, 2)

  for (int t = 0; t < 99; t += 3) {
    CH_STEP(Pa, t)
    if (t + 3 < T_STEPS) CH_LOAD(Pa, t + 3)
    CH_STEP(Pb, t + 1)
    if (t + 4 < T_STEPS) CH_LOAD(Pb, t + 4)
    CH_STEP(Pc, t + 2)
    if (t + 5 < T_STEPS) CH_LOAD(Pc, t + 5)
  }
  CH_STEP(Pa, 99)

  // ---- epilogue: histogram + compacted (state, weight) list ----
  __syncthreads();
  for (int s = g; s < BB * 101; s += 64) (&scnt[0][0])[s] = 0;
  __syncthreads();
  {
    uint32_t p0 = spk[g];
    atomicAdd(&scnt[0][p0 & 255], 1);
    atomicAdd(&scnt[1][(p0 >> 8) & 255], 1);
    atomicAdd(&scnt[2][(p0 >> 16) & 255], 1);
    atomicAdd(&scnt[3][p0 >> 24], 1);
    if (g < T_STEPS - 64) {
      uint32_t p1 = spk[64 + g];
      atomicAdd(&scnt[0][p1 & 255], 1);
      atomicAdd(&scnt[1][(p1 >> 8) & 255], 1);
      atomicAdd(&scnt[2][(p1 >> 16) & 255], 1);
      atomicAdd(&scnt[3][p1 >> 24], 1);
    }
  }
  __syncthreads();
  if (g < 4) {
    int m = 0;
    for (int s = 0; s <= 100; s++) {
      int c = scnt[g][s];
      if (c) { slist[g * 104 + m] = s; wlist[g * 104 + m] = (float)c; m++; }
    }
    Mv[g] = m;
  }
}

// ---------------- Kernel E: out via compacted state list --------------------
__global__ __launch_bounds__(512) void out_kernel(const float* __restrict__ pm,
                                                  const float* __restrict__ A0,
                                                  const int* __restrict__ slist,
                                                  const float* __restrict__ wlist,
                                                  const int* __restrict__ Mv,
                                                  float* __restrict__ out) {
  int b = blockIdx.x >> 9;
  int i = blockIdx.x & 511;
  int j = threadIdx.x;
  int M = Mv[b];
  float r = 0.0f;
  for (int e = 0; e < M; e++) {
    int s = slist[b * 104 + e];
    float w = wlist[b * 104 + e];
    if (s == 0) {
      r += w * A0[(size_t)i * NN + j];
    } else {
      int t = s - 1;
      float pmi = pm[(size_t)(t * BB + b) * NN + i];
      float pmj = pm[(size_t)(t * BB + b) * NN + j];
      r += w * fast_sigmoid(__fmul_rn(pmi, pmj));
    }
  }
  out[((size_t)b * NN + i) * NN + j] = r * 0.01f;
}

extern "C" void kernel_launch(void* const* d_in, const int* in_sizes, int n_in,
                              void* d_out, int out_size, void* d_ws, size_t ws_size,
                              hipStream_t stream) {
  const float* mu  = (const float*)d_in[0];
  const float* sig = (const float*)d_in[1];
  const float* pi  = (const float*)d_in[2];
  const float* A0  = (const float*)d_in[3];

  char* ws = (char*)d_ws;
  size_t off = 0;
  auto alloc = [&](size_t bytes) -> char* {
    char* p = ws + off;
    off += (bytes + 255) & ~(size_t)255;
    return p;
  };
  float* llt   = (float*)alloc((size_t)T_STEPS * BB * NN * 4); // 819,200
  float* ll0   = (float*)alloc(BB * NN * 4);                   // 8,192
  float* pm    = (float*)alloc((size_t)T_STEPS * BB * NN * 4); // 819,200
  float* uacc  = (float*)alloc(T_STEPS * 4 * 4);
  int*   slist = (int*)alloc(BB * 104 * 4);
  float* wlist = (float*)alloc(BB * 104 * 4);
  int*   Mv    = (int*)alloc(4 * 4);
  float* outp  = (float*)d_out;

  ll_kernel<<<1616, 512, 0, stream>>>(mu, sig, pi, A0, pm, uacc, llt, ll0);
  chain_kernel<<<1, 64, 0, stream>>>(llt, ll0, uacc, slist, wlist, Mv);
  out_kernel<<<BB * NN, 512, 0, stream>>>(pm, A0, slist, wlist, Mv, outp);
}